// Round 5
// baseline (3437.794 us; speedup 1.0000x reference)
//
#include <hip/hip_runtime.h>

#define TOKENS 18
#define QLEN 9
#define HDIM 1024
#define IDIM 4096
#define NLAYER 8
#define NB 256

// ws layout (float offsets)
#define HA_OFF    0u          // h after attn-residual (or embed h0): [18][1024]
#define HF_OFF    18432u      // h after mlp-residual: [18][1024]
#define SH_OFF    36864u      // shared region: qkvp [32][18][1280] ALIASED with gup [32][18][8192]
#define OP_OFF    4755456u    // attn-out partials [32][18][1024]
#define WDP_OFF   5345280u    // mlp-down partials [128][18][1024]
#define OUTP_OFF  7704576u    // out-proj partials [32][512]
#define SSQP_OFF  7720960u    // sumsq partials [20][32][18]
#define CNT_OFF   7732480u    // 64 uints; mini-barrier cnt[0..16], grid barrier at [63]
#define TOTAL_F   7732608u    // ~30.9 MB

__device__ __forceinline__ void gsync(unsigned* bar, unsigned target) {
  __syncthreads();
  if (threadIdx.x == 0) {
    __threadfence();
    __hip_atomic_fetch_add(bar, 1u, __ATOMIC_RELEASE, __HIP_MEMORY_SCOPE_AGENT);
    while (__hip_atomic_load(bar, __ATOMIC_ACQUIRE, __HIP_MEMORY_SCOPE_AGENT) < target)
      __builtin_amdgcn_s_sleep(4);
  }
  __syncthreads();
}

__global__ void __launch_bounds__(256) k_persist(
    const float* __restrict__ rnd, const float* __restrict__ dit,
    const float* __restrict__ feat, const float* __restrict__ cfg,
    const float* __restrict__ cfgm, const float* __restrict__ t_all,
    const float* __restrict__ dt_all, const float* __restrict__ cosq,
    const float* __restrict__ sinq, const float* __restrict__ W_in,
    const float* __restrict__ b_in, const float* __restrict__ ln1,
    const float* __restrict__ Wq, const float* __restrict__ Wk,
    const float* __restrict__ Wv, const float* __restrict__ Wo,
    const float* __restrict__ ln2, const float* __restrict__ Wg,
    const float* __restrict__ Wu, const float* __restrict__ Wd,
    const float* __restrict__ normw, const float* __restrict__ Wout,
    const float* __restrict__ bout, const int* __restrict__ step,
    float* __restrict__ ws, float* __restrict__ out) {
  const int bid = blockIdx.x, tid = threadIdx.x;
  unsigned* cnt = (unsigned*)(ws + CNT_OFF);
  unsigned* gbar = cnt + 63;
  __shared__ float smem[4608];
  unsigned gen = 0;

  // ================= embed: HA := h0 =================
  if (bid < 32) {
    int d0 = bid * 32;
    int st = step[0];
    for (int i = tid; i < 576; i += 256) {
      int r = i & 31, t = i >> 5;
      int d = d0 + r;
      int b = t / QLEN, q = t - b * QLEN;
      float v;
      if (q == 0) {
        v = t_all[(size_t)st * HDIM + d] + (b == 0 ? dit[d] : 0.f);
      } else if (q <= 4) {
        v = feat[(size_t)(b * 4 + q - 1) * HDIM + d];
      } else {
        int p = q - 5;
        float acc = b_in[d];
#pragma unroll 8
        for (int f = 0; f < 64; f++) acc += rnd[p * 64 + f] * W_in[(size_t)f * HDIM + d];
        v = acc;
      }
      ws[HA_OFF + (size_t)t * HDIM + d] = v;
    }
  }
  gen++; gsync(gbar, gen * NB);

  for (int l = 0; l < NLAYER; l++) {
    // ============ A: qkv partials = rms(h_f)*ln1 @ [Wq|Wk|Wv] ============
    if (bid < 160) {
      int cg = bid % 5, ks = bid / 5, r0 = ks * 32;
      int slot = l;
      // inline input: h_f = HA + sum(wdp)  (l==0: just HA = h0)
      for (int i = tid; i < 576; i += 256) {
        int r = i & 31, t = i >> 5;
        float v = ws[HA_OFF + (size_t)t * HDIM + r0 + r];
        if (l > 0) {
          const float* pp = ws + WDP_OFF + (size_t)t * HDIM + r0 + r;
#pragma unroll 4
          for (int p = 0; p < 128; p++) v += pp[(size_t)p * (TOKENS * HDIM)];
        }
        smem[r * 18 + t] = v;
      }
      __syncthreads();
      if (cg == 0) {
        for (int i = tid; i < 576; i += 256) {
          int r = i & 31, t = i >> 5;
          ws[HF_OFF + (size_t)t * HDIM + r0 + r] = smem[r * 18 + t];
        }
        if (tid < 18) {
          float s = 0.f;
          for (int r = 0; r < 32; r++) { float x = smem[r * 18 + tid]; s += x * x; }
          ws[SSQP_OFF + (size_t)(slot * 32 + ks) * 18 + tid] = s;
        }
        __syncthreads();
        if (tid == 0) {
          __threadfence();
          __hip_atomic_fetch_add(&cnt[slot], 1u, __ATOMIC_RELEASE, __HIP_MEMORY_SCOPE_AGENT);
        }
      }
      __syncthreads();
      // ln1 multiply is folded into the weight read below (avoids in-place smem hazard)
      const float* lw = ln1 + (size_t)l * HDIM;
      int col = cg * 256 + tid;
      const float* wp; int stride;
      if (col < 1024)      { wp = Wq + ((size_t)l << 20) + col;            stride = 1024; }
      else if (col < 1152) { wp = Wk + (size_t)l * 131072 + (col - 1024);  stride = 128;  }
      else                 { wp = Wv + (size_t)l * 131072 + (col - 1152);  stride = 128;  }
      wp += (size_t)r0 * stride;
      float acc[TOKENS];
#pragma unroll
      for (int t = 0; t < TOKENS; t++) acc[t] = 0.f;
#pragma unroll 8
      for (int r = 0; r < 32; r++) {
        float w = wp[(size_t)r * stride] * lw[r0 + r];
#pragma unroll
        for (int t = 0; t < TOKENS; t++) acc[t] += smem[r * 18 + t] * w;
      }
      if (tid == 0) {
        while (__hip_atomic_load(&cnt[slot], __ATOMIC_ACQUIRE, __HIP_MEMORY_SCOPE_AGENT) < 32u)
          __builtin_amdgcn_s_sleep(2);
      }
      __syncthreads();
      if (tid < 18) {
        float s = 0.f;
        const float* sp = ws + SSQP_OFF + (size_t)slot * 32 * 18 + tid;
        for (int j = 0; j < 32; j++) s += sp[j * 18];
        smem[576 + tid] = rsqrtf(s * (1.f / HDIM) + 1e-6f);
      }
      __syncthreads();
      {
        float* qp = ws + SH_OFF + (size_t)ks * (TOKENS * 1280) + col;
#pragma unroll
        for (int t = 0; t < TOKENS; t++) qp[(size_t)t * 1280] = acc[t] * smem[576 + t];
      }
    }
    gen++; gsync(gbar, gen * NB);

    // ============ B: attn + Wo partials (inline qkv reduce) ============
    if (bid < 128) {
      int bx = bid & 3, by = bid >> 2;
      int r0 = by * 32;
      int head = r0 >> 6, kvh = head >> 3, d0 = r0 & 63;
      float* lq = smem;            // [18][68]
      float* lk = smem + 1224;     // [18][68]
      float* lv = smem + 2448;     // [18][36]
      float* sP = smem + 3096;     // [18][12]
      float* sA = smem + 3312;     // [32][18]
      for (int i = tid; i < 2 * QLEN * 64; i += 256) {
        int d = i & 63, qi = (i >> 6) % QLEN, b = i / (QLEN * 64);
        int row = b * QLEN + qi;
        const float* qp = ws + SH_OFF + (size_t)row * 1280 + head * 64 + d;
        const float* kp = ws + SH_OFF + (size_t)row * 1280 + 1024 + kvh * 64 + d;
        float qs = 0.f, ks2 = 0.f;
#pragma unroll 4
        for (int p = 0; p < 32; p++) {
          qs  += qp[(size_t)p * (TOKENS * 1280)];
          ks2 += kp[(size_t)p * (TOKENS * 1280)];
        }
        lq[row * 68 + d] = qs;
        lk[row * 68 + d] = ks2;
      }
      for (int i = tid; i < 2 * QLEN * 32; i += 256) {
        int d = i & 31, ki = (i >> 5) % QLEN, b = i / (QLEN * 32);
        int row = b * QLEN + ki;
        const float* vp = ws + SH_OFF + (size_t)row * 1280 + 1152 + kvh * 64 + d0 + d;
        float vs = 0.f;
#pragma unroll 4
        for (int p = 0; p < 32; p++) vs += vp[(size_t)p * (TOKENS * 1280)];
        lv[row * 36 + d] = vs;
      }
      __syncthreads();
      // RoPE in place (pairwise halves; cos/sin include DH^-0.25)
      for (int i = tid; i < 2 * QLEN * 32; i += 256) {
        int d = i & 31, qi = (i >> 5) % QLEN, b = i / (QLEN * 32);
        int base = (b * QLEN + qi) * 68;
        float c1 = cosq[qi * 64 + d],      s1 = sinq[qi * 64 + d];
        float c2 = cosq[qi * 64 + 32 + d], s2 = sinq[qi * 64 + 32 + d];
        float qa = lq[base + d], qb = lq[base + 32 + d];
        lq[base + d]      = qa * c1 - qb * s1;
        lq[base + 32 + d] = qb * c2 + qa * s2;
        float ka = lk[base + d], kb = lk[base + 32 + d];
        lk[base + d]      = ka * c1 - kb * s1;
        lk[base + 32 + d] = kb * c2 + ka * s2;
      }
      __syncthreads();
      for (int i = tid; i < 2 * QLEN * QLEN; i += 256) {
        int ki = i % QLEN, qi = (i / QLEN) % QLEN, b = i / (QLEN * QLEN);
        float s = 0.f;
#pragma unroll
        for (int d = 0; d < 64; d++) s += lq[(b * QLEN + qi) * 68 + d] * lk[(b * QLEN + ki) * 68 + d];
        sP[(b * QLEN + qi) * 12 + ki] = s;
      }
      __syncthreads();
      if (tid < TOKENS) {
        float m = -1e30f;
#pragma unroll
        for (int k = 0; k < QLEN; k++) m = fmaxf(m, sP[tid * 12 + k]);
        float e[QLEN], sum = 0.f;
#pragma unroll
        for (int k = 0; k < QLEN; k++) { e[k] = expf(sP[tid * 12 + k] - m); sum += e[k]; }
        float inv = 1.f / sum;
#pragma unroll
        for (int k = 0; k < QLEN; k++) sP[tid * 12 + k] = e[k] * inv;
      }
      __syncthreads();
      for (int i = tid; i < 32 * TOKENS; i += 256) {
        int dd = i / TOKENS, t = i - dd * TOKENS;
        int b = t / QLEN;
        float a = 0.f;
#pragma unroll
        for (int k = 0; k < QLEN; k++) a += sP[t * 12 + k] * lv[(b * QLEN + k) * 36 + dd];
        sA[dd * 18 + t] = a;
      }
      __syncthreads();
      int col = bx * 256 + tid;
      const float* wp = Wo + ((size_t)l << 20) + (size_t)r0 * 1024 + col;
      float acc[TOKENS];
#pragma unroll
      for (int t = 0; t < TOKENS; t++) acc[t] = 0.f;
#pragma unroll 8
      for (int r = 0; r < 32; r++) {
        float w = wp[(size_t)r * 1024];
#pragma unroll
        for (int t = 0; t < TOKENS; t++) acc[t] += sA[r * 18 + t] * w;
      }
#pragma unroll
      for (int t = 0; t < TOKENS; t++)
        ws[OP_OFF + (size_t)(by * TOKENS + t) * 1024 + col] = acc[t];
    }
    gen++; gsync(gbar, gen * NB);

    // ============ D: gu partials = rms(h_a)*ln2 @ [Wg|Wu] (inline o-reduce) ============
    {
      int cg = bid & 7, ks = bid >> 3, r0 = ks * 32;
      int slot = 8 + l;
      for (int i = tid; i < 576; i += 256) {
        int r = i & 31, t = i >> 5;
        float v = ws[HF_OFF + (size_t)t * HDIM + r0 + r];
        const float* pp = ws + OP_OFF + (size_t)t * HDIM + r0 + r;
#pragma unroll 4
        for (int p = 0; p < 32; p++) v += pp[(size_t)p * (TOKENS * HDIM)];
        smem[r * 18 + t] = v;
      }
      __syncthreads();
      if (cg == 0) {
        for (int i = tid; i < 576; i += 256) {
          int r = i & 31, t = i >> 5;
          ws[HA_OFF + (size_t)t * HDIM + r0 + r] = smem[r * 18 + t];
        }
        if (tid < 18) {
          float s = 0.f;
          for (int r = 0; r < 32; r++) { float x = smem[r * 18 + tid]; s += x * x; }
          ws[SSQP_OFF + (size_t)(slot * 32 + ks) * 18 + tid] = s;
        }
        __syncthreads();
        if (tid == 0) {
          __threadfence();
          __hip_atomic_fetch_add(&cnt[slot], 1u, __ATOMIC_RELEASE, __HIP_MEMORY_SCOPE_AGENT);
        }
      }
      __syncthreads();
      const float* lw = ln2 + (size_t)l * HDIM;
      int colm = (cg & 3) * 1024 + tid * 4;
      const float* W = (cg < 4 ? Wg : Wu) + ((size_t)l << 22);
      const float* wp = W + (size_t)r0 * IDIM + colm;
      float4 acc[TOKENS];
#pragma unroll
      for (int t = 0; t < TOKENS; t++) acc[t] = make_float4(0.f, 0.f, 0.f, 0.f);
#pragma unroll 4
      for (int r = 0; r < 32; r++) {
        float4 w = *reinterpret_cast<const float4*>(wp + (size_t)r * IDIM);
        float lwv = lw[r0 + r];
        w.x *= lwv; w.y *= lwv; w.z *= lwv; w.w *= lwv;
#pragma unroll
        for (int t = 0; t < TOKENS; t++) {
          float bv = smem[r * 18 + t];
          acc[t].x += bv * w.x; acc[t].y += bv * w.y;
          acc[t].z += bv * w.z; acc[t].w += bv * w.w;
        }
      }
      if (tid == 0) {
        while (__hip_atomic_load(&cnt[slot], __ATOMIC_ACQUIRE, __HIP_MEMORY_SCOPE_AGENT) < 32u)
          __builtin_amdgcn_s_sleep(2);
      }
      __syncthreads();
      if (tid < 18) {
        float s = 0.f;
        const float* sp = ws + SSQP_OFF + (size_t)slot * 32 * 18 + tid;
        for (int j = 0; j < 32; j++) s += sp[j * 18];
        smem[576 + tid] = rsqrtf(s * (1.f / HDIM) + 1e-6f);
      }
      __syncthreads();
      {
        int cbase = cg * 1024 + tid * 4;
        float* gp = ws + SH_OFF + (size_t)ks * (TOKENS * 8192) + cbase;
#pragma unroll
        for (int t = 0; t < TOKENS; t++) {
          float rs = smem[576 + t];
          float4 o = make_float4(acc[t].x * rs, acc[t].y * rs, acc[t].z * rs, acc[t].w * rs);
          *reinterpret_cast<float4*>(gp + (size_t)t * 8192) = o;
        }
      }
    }
    gen++; gsync(gbar, gen * NB);

    // ============ E: wd partials = silu(g)*u @ Wd (inline gu-reduce) ============
    {
      int ch = bid & 1, ks = bid >> 1, r0 = ks * 32;
      for (int i = tid; i < 576; i += 256) {
        int r = i & 31, t = i >> 5;
        const float* gp = ws + SH_OFF + (size_t)t * 8192 + r0 + r;
        float g = 0.f, u = 0.f;
#pragma unroll 4
        for (int p = 0; p < 32; p++) {
          g += gp[(size_t)p * (TOKENS * 8192)];
          u += gp[(size_t)p * (TOKENS * 8192) + 4096];
        }
        smem[r * 18 + t] = (g / (1.f + expf(-g))) * u;
      }
      __syncthreads();
      int c = ch * 512 + tid * 2;
      const float* wp = Wd + ((size_t)l << 22) + (size_t)r0 * HDIM + c;
      float2 acc[TOKENS];
#pragma unroll
      for (int t = 0; t < TOKENS; t++) acc[t] = make_float2(0.f, 0.f);
#pragma unroll 4
      for (int r = 0; r < 32; r++) {
        float2 w = *reinterpret_cast<const float2*>(wp + (size_t)r * HDIM);
#pragma unroll
        for (int t = 0; t < TOKENS; t++) {
          float bv = smem[r * 18 + t];
          acc[t].x += bv * w.x; acc[t].y += bv * w.y;
        }
      }
#pragma unroll
      for (int t = 0; t < TOKENS; t++)
        *reinterpret_cast<float2*>(ws + WDP_OFF + (size_t)(ks * TOKENS + t) * 1024 + c) = acc[t];
    }
    gen++; gsync(gbar, gen * NB);
  }

  // ================= G: out-proj partials =================
  if (bid < 8) {
    int r0 = bid * 128;
    for (int i = tid; i < 1024; i += 256) {
      int r = i >> 3, s = i & 7;
      int t = (s >> 2) * QLEN + 5 + (s & 3);
      float v = ws[HA_OFF + (size_t)t * HDIM + r0 + r];
      const float* pp = ws + WDP_OFF + (size_t)t * HDIM + r0 + r;
#pragma unroll 4
      for (int p = 0; p < 128; p++) v += pp[(size_t)p * (TOKENS * HDIM)];
      smem[r * 8 + s] = v;
    }
    __syncthreads();
    if (tid < 8) {
      float ss = 0.f;
      for (int r = 0; r < 128; r++) { float x = smem[r * 8 + tid]; ss += x * x; }
      ws[SSQP_OFF + (size_t)(16 * 32 + bid) * 18 + tid] = ss;
    }
    __syncthreads();
    if (tid == 0) {
      __threadfence();
      __hip_atomic_fetch_add(&cnt[16], 1u, __ATOMIC_RELEASE, __HIP_MEMORY_SCOPE_AGENT);
    }
    int colc = tid & 63, rsub = tid >> 6;
    const float* wp = Wout + (size_t)(r0 + rsub * 32) * 64 + colc;
    float acc[8];
#pragma unroll
    for (int s = 0; s < 8; s++) acc[s] = 0.f;
#pragma unroll 4
    for (int r = 0; r < 32; r++) {
      float w = wp[(size_t)r * 64];
      float nw = normw[r0 + rsub * 32 + r];
#pragma unroll
      for (int s = 0; s < 8; s++) acc[s] += smem[(rsub * 32 + r) * 8 + s] * nw * w;
    }
    if (tid == 0) {
      while (__hip_atomic_load(&cnt[16], __ATOMIC_ACQUIRE, __HIP_MEMORY_SCOPE_AGENT) < 8u)
        __builtin_amdgcn_s_sleep(2);
    }
    __syncthreads();
    if (tid < 8) {
      float s = 0.f;
      const float* sp = ws + SSQP_OFF + (size_t)(16 * 32) * 18 + tid;
      for (int j = 0; j < 8; j++) s += sp[j * 18];
      smem[1024 + tid] = rsqrtf(s * (1.f / HDIM) + 1e-6f);
    }
    __syncthreads();
#pragma unroll
    for (int s = 0; s < 8; s++)
      ws[OUTP_OFF + (size_t)(bid * 4 + rsub) * 512 + s * 64 + colc] = acc[s] * smem[1024 + s];
  }
  gen++; gsync(gbar, gen * NB);

  // ================= H: cfg combine + write out =================
  if (bid == 0) {
    int f = tid & 63;
    float pv = bout[f], nv = bout[f];
#pragma unroll 4
    for (int pp = 0; pp < 32; pp++) {
      pv += ws[OUTP_OFF + (size_t)pp * 512 + tid];
      nv += ws[OUTP_OFF + (size_t)pp * 512 + 256 + tid];
    }
    float pn = pv * nv, nn = nv * nv;
#pragma unroll
    for (int off = 32; off >= 1; off >>= 1) {
      pn += __shfl_down(pn, off);
      nn += __shfl_down(nn, off);
    }
    int wave = tid >> 6, lane = tid & 63;
    if (lane == 0) { smem[wave] = pn; smem[4 + wave] = nn; }
    __syncthreads();
    if (tid == 0) {
      float PN = smem[0] + smem[1] + smem[2] + smem[3];
      float NN = smem[4] + smem[5] + smem[6] + smem[7];
      smem[8] = PN / (NN + 1e-7f);
    }
    __syncthreads();
    int st = step[0];
    float dphi = cfgm[0] * nv * smem[8] + cfg[0] * pv;
    out[1 + tid] = rnd[tid] - dt_all[st] * dphi;
    if (tid == 0) out[0] = (float)(st + 1);
  }
}

// ---------------- launch ------------------------------------------------------------
extern "C" void kernel_launch(void* const* d_in, const int* in_sizes, int n_in,
                              void* d_out, int out_size, void* d_ws, size_t ws_size,
                              hipStream_t stream) {
  const float* rnd   = (const float*)d_in[0];
  const float* dit   = (const float*)d_in[1];
  const float* feat  = (const float*)d_in[2];
  const float* cfg   = (const float*)d_in[3];
  const float* cfgm  = (const float*)d_in[4];
  const float* t_all = (const float*)d_in[5];
  const float* dt_al = (const float*)d_in[6];
  const float* cosq  = (const float*)d_in[7];
  const float* sinq  = (const float*)d_in[8];
  const float* W_in  = (const float*)d_in[9];
  const float* b_in  = (const float*)d_in[10];
  const float* ln1   = (const float*)d_in[11];
  const float* Wq    = (const float*)d_in[12];
  const float* Wk    = (const float*)d_in[13];
  const float* Wv    = (const float*)d_in[14];
  const float* Wo    = (const float*)d_in[15];
  const float* ln2   = (const float*)d_in[16];
  const float* Wg    = (const float*)d_in[17];
  const float* Wu    = (const float*)d_in[18];
  const float* Wd    = (const float*)d_in[19];
  const float* normw = (const float*)d_in[20];
  const float* Wout  = (const float*)d_in[21];
  const float* bout  = (const float*)d_in[22];
  const int*   step  = (const int*)d_in[23];
  float* ws = (float*)d_ws;

  // zero barrier + mini-barrier counters (256 B) — everything else is written before read
  hipMemsetAsync((void*)(ws + CNT_OFF), 0, 64 * sizeof(unsigned), stream);
  k_persist<<<NB, 256, 0, stream>>>(rnd, dit, feat, cfg, cfgm, t_all, dt_al,
                                    cosq, sinq, W_in, b_in, ln1, Wq, Wk, Wv, Wo,
                                    ln2, Wg, Wu, Wd, normw, Wout, bout, step,
                                    ws, (float*)d_out);
}

// Round 6
// 620.563 us; speedup vs baseline: 5.5398x; 5.5398x over previous
//
#include <hip/hip_runtime.h>

#define TOKENS 18
#define QLEN 9
#define HDIM 1024
#define IDIM 4096
#define NLAYER 8

// ws layout (float offsets)
#define H_OFF     0u           // h: [18][1024]
#define QKV_OFF   18432u       // reduced qkv: [18][1280]
#define QKVP_OFF  41472u       // qkv partials: [128][18][1280]
#define OPP_OFF   2990592u     // attn-out partials: [256][18][1024]
#define WDP_OFF   7709184u     // mlp-down partials: [256][18][1024]
#define GUP_OFF   12427776u    // gu partials: [32][18][8192]
#define OUTP_OFF  17146368u    // out partials: [32][512]
#define TOTAL_F   17162752u    // ~68.7 MB

// ---------------- helpers: deep-prefetch GEMV inner loops ---------------------------
__device__ __forceinline__ void load8(float4* buf, const float* wp, int cc, int stride) {
#pragma unroll
  for (int j = 0; j < 8; j++)
    buf[j] = *reinterpret_cast<const float4*>(wp + (size_t)(cc * 8 + j) * stride);
}
__device__ __forceinline__ void fma8(float4* acc, const float4* buf,
                                     const float (*sb)[TOKENS], int cc) {
#pragma unroll
  for (int j = 0; j < 8; j++) {
#pragma unroll
    for (int t = 0; t < TOKENS; t++) {
      float bv = sb[cc * 8 + j][t];
      acc[t].x += bv * buf[j].x; acc[t].y += bv * buf[j].y;
      acc[t].z += bv * buf[j].z; acc[t].w += bv * buf[j].w;
    }
  }
}

// ---------------- rstd over all 18 h-rows (block-wide, h is L2-resident) -------------
__device__ __forceinline__ void block_rstd18(const float* __restrict__ h,
                                             float* s_rstd, float* s_red) {
  int tid = threadIdx.x;
  float ss[TOKENS];
#pragma unroll
  for (int t = 0; t < TOKENS; t++) {
    float4 v = reinterpret_cast<const float4*>(h + (size_t)t * HDIM)[tid];
    ss[t] = v.x*v.x + v.y*v.y + v.z*v.z + v.w*v.w;
  }
#pragma unroll
  for (int off = 32; off >= 1; off >>= 1) {
#pragma unroll
    for (int t = 0; t < TOKENS; t++) ss[t] += __shfl_down(ss[t], off);
  }
  int wave = tid >> 6, lane = tid & 63;
  if (lane == 0) {
#pragma unroll
    for (int t = 0; t < TOKENS; t++) s_red[wave * TOKENS + t] = ss[t];
  }
  __syncthreads();
  if (tid < TOKENS) {
    float tot = s_red[tid] + s_red[TOKENS + tid] + s_red[2*TOKENS + tid] + s_red[3*TOKENS + tid];
    s_rstd[tid] = rsqrtf(tot * (1.0f / HDIM) + 1e-6f);
  }
  __syncthreads();
}

// ---------------- tree reducer: dst[e] (+)= sum_p src[p*n+e], 4 waves per element ---
__global__ __launch_bounds__(256) void k_red4(
    const float* __restrict__ src, float* __restrict__ dst,
    int nparts, int n, int accum) {
  int le = threadIdx.x & 63, j = threadIdx.x >> 6;
  int e = blockIdx.x * 64 + le;
  float s = 0.f;
#pragma unroll 8
  for (int p = j; p < nparts; p += 4) s += src[(size_t)p * n + e];
  __shared__ float red[4][64];
  red[j][le] = s;
  __syncthreads();
  if (j == 0) {
    float tot = red[0][le] + red[1][le] + red[2][le] + red[3][le];
    dst[e] = accum ? dst[e] + tot : tot;
  }
}

// ---------------- K0: build h (2,9,1024) --------------------------------------------
__global__ __launch_bounds__(256) void k_embed(
    const float* __restrict__ rnd, const float* __restrict__ dit,
    const float* __restrict__ feat, const float* __restrict__ t_all,
    const float* __restrict__ W_in, const float* __restrict__ b_in,
    const int* __restrict__ step, float* __restrict__ ws) {
  float* h = ws;
  int bid = blockIdx.x, tid = threadIdx.x;
  int st = step[0];
  const float* t = t_all + (size_t)st * HDIM;
  if (bid < 2) {
    int b = bid;
    for (int c = tid; c < HDIM; c += 256) {
      float v = t[c];
      if (b == 0) v += dit[c];
      h[(size_t)(b * QLEN) * HDIM + c] = v;
    }
  } else if (bid < 10) {
    int i = bid - 2;
    int b = i >> 2, p = i & 3;
    for (int c = tid; c < HDIM; c += 256)
      h[(size_t)(b * QLEN + 1 + p) * HDIM + c] = feat[(size_t)(b * 4 + p) * HDIM + c];
  } else {
    int p = bid - 10;
    __shared__ float rl[64];
    if (tid < 64) rl[tid] = rnd[p * 64 + tid];
    __syncthreads();
    for (int c = tid; c < HDIM; c += 256) {
      float acc = b_in[c];
#pragma unroll 8
      for (int f = 0; f < 64; f++) acc += rl[f] * W_in[(size_t)f * HDIM + c];
      h[(size_t)(5 + p) * HDIM + c] = acc;
      h[(size_t)(QLEN + 5 + p) * HDIM + c] = acc;
    }
  }
}

// ---------------- K1: qkv partials (8-row k-chunks, 128 splits) ---------------------
__global__ __launch_bounds__(256) void k_qkv(
    const float* __restrict__ Wq, const float* __restrict__ Wk,
    const float* __restrict__ Wv, const float* __restrict__ ln1,
    float* __restrict__ ws, int layer) {
  const float* h = ws;
  __shared__ float s_rstd[TOKENS];
  __shared__ float s_red[4 * TOKENS];
  __shared__ float s_b[8][TOKENS];
  int tid = threadIdx.x;
  block_rstd18(h, s_rstd, s_red);
  int r0 = blockIdx.y * 8;
  const float* lw = ln1 + (size_t)layer * HDIM;
  for (int i = tid; i < 8 * TOKENS; i += 256) {
    int r = i / TOKENS, t = i - r * TOKENS;
    s_b[r][t] = h[(size_t)t * HDIM + r0 + r] * lw[r0 + r];
  }
  __syncthreads();
  float* qpb = ws + QKVP_OFF + (size_t)blockIdx.y * (TOKENS * 1280);
  if (blockIdx.x == 0) {
    int c = tid * 4;
    const float* wp = Wq + ((size_t)layer << 20) + (size_t)r0 * HDIM + c;
    float4 A[8];
    load8(A, wp, 0, HDIM);
    float4 acc[TOKENS];
#pragma unroll
    for (int t = 0; t < TOKENS; t++) acc[t] = make_float4(0.f, 0.f, 0.f, 0.f);
    fma8(acc, A, s_b, 0);
#pragma unroll
    for (int t = 0; t < TOKENS; t++) {
      float rs = s_rstd[t];
      float4 o = make_float4(acc[t].x*rs, acc[t].y*rs, acc[t].z*rs, acc[t].w*rs);
      *reinterpret_cast<float4*>(qpb + (size_t)t * 1280 + c) = o;
    }
  } else if (tid < 64) {
    int c = 1024 + tid * 4;
    const float* wp;
    if (c < 1152) wp = Wk + (size_t)layer * 131072 + (size_t)r0 * 128 + (c - 1024);
    else          wp = Wv + (size_t)layer * 131072 + (size_t)r0 * 128 + (c - 1152);
    float4 A[8];
    load8(A, wp, 0, 128);
    float4 acc[TOKENS];
#pragma unroll
    for (int t = 0; t < TOKENS; t++) acc[t] = make_float4(0.f, 0.f, 0.f, 0.f);
    fma8(acc, A, s_b, 0);
#pragma unroll
    for (int t = 0; t < TOKENS; t++) {
      float rs = s_rstd[t];
      float4 o = make_float4(acc[t].x*rs, acc[t].y*rs, acc[t].z*rs, acc[t].w*rs);
      *reinterpret_cast<float4*>(qpb + (size_t)t * 1280 + c) = o;
    }
  }
}

// ---------------- K2: attn recompute + Wo partials (4-row chunks, 256 splits) -------
__global__ __launch_bounds__(256) void k_attn(
    const float* __restrict__ Wo, const float* __restrict__ cosq,
    const float* __restrict__ sinq, float* __restrict__ ws, int layer) {
  const float* qkv = ws + QKV_OFF;
  int by = blockIdx.x;
  float* op = ws + OPP_OFF + (size_t)by * (TOKENS * HDIM);
  __shared__ float lq[2][QLEN][68];
  __shared__ float lk[2][QLEN][68];
  __shared__ float lv[2][QLEN][4];
  __shared__ float sP[2][QLEN][12];
  __shared__ float sA[4][TOKENS];
  int tid = threadIdx.x;
  int r0 = by * 4;
  int head = r0 >> 6;
  int kvh = head >> 3;
  int d0 = r0 & 63;
  for (int i = tid; i < 2 * QLEN * 64; i += 256) {
    int d = i & 63;
    int qi = (i >> 6) % QLEN;
    int b = i / (QLEN * 64);
    const float* qr = qkv + (size_t)(b * QLEN + qi) * 1280;
    float c = cosq[qi * 64 + d], s = sinq[qi * 64 + d];
    float qv = qr[head * 64 + d];
    float qo = (d < 32) ? -qr[head * 64 + d + 32] : qr[head * 64 + d - 32];
    lq[b][qi][d] = qv * c + qo * s;
    float kv = qr[1024 + kvh * 64 + d];
    float ko = (d < 32) ? -qr[1024 + kvh * 64 + d + 32] : qr[1024 + kvh * 64 + d - 32];
    lk[b][qi][d] = kv * c + ko * s;
  }
  for (int i = tid; i < 2 * QLEN * 4; i += 256) {
    int d = i & 3;
    int ki = (i >> 2) % QLEN;
    int b = i / (QLEN * 4);
    lv[b][ki][d] = qkv[(size_t)(b * QLEN + ki) * 1280 + 1152 + kvh * 64 + d0 + d];
  }
  __syncthreads();
  for (int i = tid; i < 2 * QLEN * QLEN; i += 256) {
    int ki = i % QLEN;
    int qi = (i / QLEN) % QLEN;
    int b = i / (QLEN * QLEN);
    float s = 0.f;
#pragma unroll
    for (int d = 0; d < 64; d++) s += lq[b][qi][d] * lk[b][ki][d];
    sP[b][qi][ki] = s;
  }
  __syncthreads();
  if (tid < TOKENS) {
    int b = tid / QLEN, qi = tid % QLEN;
    float m = -1e30f;
#pragma unroll
    for (int k = 0; k < QLEN; k++) m = fmaxf(m, sP[b][qi][k]);
    float e[QLEN], sum = 0.f;
#pragma unroll
    for (int k = 0; k < QLEN; k++) { e[k] = expf(sP[b][qi][k] - m); sum += e[k]; }
    float inv = 1.f / sum;
#pragma unroll
    for (int k = 0; k < QLEN; k++) sP[b][qi][k] = e[k] * inv;
  }
  __syncthreads();
  for (int i = tid; i < 4 * TOKENS; i += 256) {
    int dd = i / TOKENS, t = i - dd * TOKENS;
    int b = t / QLEN, qi = t % QLEN;
    float a = 0.f;
#pragma unroll
    for (int k = 0; k < QLEN; k++) a += sP[b][qi][k] * lv[b][k][dd];
    sA[dd][t] = a;
  }
  __syncthreads();
  int c = tid * 4;
  const float* wp = Wo + ((size_t)layer << 20) + (size_t)r0 * HDIM + c;
  float4 wv[4];
#pragma unroll
  for (int r = 0; r < 4; r++)
    wv[r] = *reinterpret_cast<const float4*>(wp + (size_t)r * HDIM);
  float4 acc[TOKENS];
#pragma unroll
  for (int t = 0; t < TOKENS; t++) acc[t] = make_float4(0.f, 0.f, 0.f, 0.f);
#pragma unroll
  for (int r = 0; r < 4; r++) {
#pragma unroll
    for (int t = 0; t < TOKENS; t++) {
      float bv = sA[r][t];
      acc[t].x += bv * wv[r].x; acc[t].y += bv * wv[r].y;
      acc[t].z += bv * wv[r].z; acc[t].w += bv * wv[r].w;
    }
  }
#pragma unroll
  for (int t = 0; t < TOKENS; t++)
    *reinterpret_cast<float4*>(op + (size_t)t * HDIM + c) = acc[t];
}

// ---------------- K3: gu partials (32-row chunks, 32 splits, dbuf prefetch) ---------
__global__ __launch_bounds__(256) void k_gu(
    const float* __restrict__ Wg, const float* __restrict__ Wu,
    const float* __restrict__ ln2, float* __restrict__ ws, int layer) {
  const float* h = ws;
  __shared__ float s_rstd[TOKENS];
  __shared__ float s_red[4 * TOKENS];
  __shared__ float s_b[32][TOKENS];
  int tid = threadIdx.x;
  block_rstd18(h, s_rstd, s_red);
  int cg = blockIdx.x, ks = blockIdx.y, r0 = ks * 32;
  const float* lw = ln2 + (size_t)layer * HDIM;
  for (int i = tid; i < 32 * TOKENS; i += 256) {
    int r = i / TOKENS, t = i - r * TOKENS;
    s_b[r][t] = h[(size_t)t * HDIM + r0 + r] * lw[r0 + r];
  }
  __syncthreads();
  const float* W = (cg < 4 ? Wg : Wu) + ((size_t)layer << 22);
  int c = (cg & 3) * 1024 + tid * 4;
  const float* wp = W + (size_t)r0 * IDIM + c;
  float4 A[8], B[8];
  float4 acc[TOKENS];
#pragma unroll
  for (int t = 0; t < TOKENS; t++) acc[t] = make_float4(0.f, 0.f, 0.f, 0.f);
  load8(A, wp, 0, IDIM);
  load8(B, wp, 1, IDIM);
  fma8(acc, A, s_b, 0);
  load8(A, wp, 2, IDIM);
  fma8(acc, B, s_b, 1);
  load8(B, wp, 3, IDIM);
  fma8(acc, A, s_b, 2);
  fma8(acc, B, s_b, 3);
  float* gp = ws + GUP_OFF + (size_t)ks * (TOKENS * 8192) + cg * 1024 + tid * 4;
#pragma unroll
  for (int t = 0; t < TOKENS; t++) {
    float rs = s_rstd[t];
    float4 o = make_float4(acc[t].x*rs, acc[t].y*rs, acc[t].z*rs, acc[t].w*rs);
    *reinterpret_cast<float4*>(gp + (size_t)t * 8192) = o;
  }
}

// ---------------- K4: wd partials (16-row chunks of IDIM, 256 splits) ---------------
__global__ __launch_bounds__(256) void k_wd(
    const float* __restrict__ Wd, float* __restrict__ ws, int layer) {
  const float* gup = ws + GUP_OFF;
  int by = blockIdx.x;
  int r0 = by * 16;
  __shared__ float s_b[16][TOKENS];
  int tid = threadIdx.x;
  for (int i = tid; i < 16 * TOKENS; i += 256) {
    int r = i / TOKENS, t = i - r * TOKENS;
    const float* base = gup + (size_t)t * 8192 + r0 + r;
    float g = 0.f, u = 0.f;
#pragma unroll 8
    for (int p = 0; p < 32; p++) {
      g += base[(size_t)p * (TOKENS * 8192)];
      u += base[(size_t)p * (TOKENS * 8192) + 4096];
    }
    s_b[r][t] = (g / (1.f + expf(-g))) * u;
  }
  __syncthreads();
  int c = tid * 4;
  const float* wp = Wd + ((size_t)layer << 22) + (size_t)r0 * HDIM + c;
  float4 A[8], B[8];
  float4 acc[TOKENS];
#pragma unroll
  for (int t = 0; t < TOKENS; t++) acc[t] = make_float4(0.f, 0.f, 0.f, 0.f);
  load8(A, wp, 0, HDIM);
  load8(B, wp, 1, HDIM);
  fma8(acc, A, s_b, 0);
  fma8(acc, B, s_b, 1);
  float* wdp = ws + WDP_OFF + (size_t)by * (TOKENS * HDIM);
#pragma unroll
  for (int t = 0; t < TOKENS; t++)
    *reinterpret_cast<float4*>(wdp + (size_t)t * HDIM + c) = acc[t];
}

// ---------------- Kf1: outb partials = rms(h[:,5:])*norm_w @ W_out ------------------
__global__ __launch_bounds__(256) void k_out(
    const float* __restrict__ Wout, const float* __restrict__ normw,
    float* __restrict__ ws) {
  const float* h = ws;
  float* outp = ws + OUTP_OFF;
  __shared__ float s_rstd[8];
  __shared__ float s_red[32];
  __shared__ float s_b[128][8];
  int tid = threadIdx.x;
  float ss[8];
#pragma unroll
  for (int s = 0; s < 8; s++) {
    int tix = (s >> 2) * QLEN + 5 + (s & 3);
    float4 v = reinterpret_cast<const float4*>(h + (size_t)tix * HDIM)[tid];
    ss[s] = v.x*v.x + v.y*v.y + v.z*v.z + v.w*v.w;
  }
#pragma unroll
  for (int off = 32; off >= 1; off >>= 1) {
#pragma unroll
    for (int s = 0; s < 8; s++) ss[s] += __shfl_down(ss[s], off);
  }
  int wave = tid >> 6, lane = tid & 63;
  if (lane == 0) {
#pragma unroll
    for (int s = 0; s < 8; s++) s_red[wave * 8 + s] = ss[s];
  }
  __syncthreads();
  if (tid < 8) {
    float tot = s_red[tid] + s_red[8 + tid] + s_red[16 + tid] + s_red[24 + tid];
    s_rstd[tid] = rsqrtf(tot * (1.f / HDIM) + 1e-6f);
  }
  __syncthreads();
  int r0 = blockIdx.x * 128;
  for (int i = tid; i < 128 * 8; i += 256) {
    int r = i >> 3, s = i & 7;
    int tix = (s >> 2) * QLEN + 5 + (s & 3);
    s_b[r][s] = h[(size_t)tix * HDIM + r0 + r] * normw[r0 + r] * s_rstd[s];
  }
  __syncthreads();
  int colc = tid & 63, rsub = tid >> 6;
  const float* wp = Wout + (size_t)(r0 + rsub * 32) * 64 + colc;
  float acc[8];
#pragma unroll
  for (int s = 0; s < 8; s++) acc[s] = 0.f;
#pragma unroll 8
  for (int r = 0; r < 32; r++) {
    float w = wp[(size_t)r * 64];
#pragma unroll
    for (int s = 0; s < 8; s++) acc[s] += s_b[rsub * 32 + r][s] * w;
  }
  float* slot = outp + (size_t)(blockIdx.x * 4 + rsub) * 512;
#pragma unroll
  for (int s = 0; s < 8; s++) slot[s * 64 + colc] = acc[s];
}

// ---------------- Kf2: cfg combine + write d_out (float32) --------------------------
__global__ __launch_bounds__(256) void k_final(
    const float* __restrict__ rnd, const float* __restrict__ cfg,
    const float* __restrict__ cfgm, const float* __restrict__ dt_all,
    const float* __restrict__ bout, const int* __restrict__ step,
    const float* __restrict__ ws, float* __restrict__ out) {
  const float* outp = ws + OUTP_OFF;
  int tid = threadIdx.x;
  int f = tid & 63;
  float p = bout[f], n = bout[f];
#pragma unroll 8
  for (int pp = 0; pp < 32; pp++) {
    p += outp[(size_t)pp * 512 + tid];
    n += outp[(size_t)pp * 512 + 256 + tid];
  }
  float pn = p * n, nn = n * n;
#pragma unroll
  for (int off = 32; off >= 1; off >>= 1) {
    pn += __shfl_down(pn, off);
    nn += __shfl_down(nn, off);
  }
  __shared__ float red[8];
  __shared__ float s_st;
  int wave = tid >> 6, lane = tid & 63;
  if (lane == 0) { red[wave] = pn; red[4 + wave] = nn; }
  __syncthreads();
  if (tid == 0) {
    float PN = red[0] + red[1] + red[2] + red[3];
    float NN = red[4] + red[5] + red[6] + red[7];
    s_st = PN / (NN + 1e-7f);
  }
  __syncthreads();
  int st = step[0];
  float dphi = cfgm[0] * n * s_st + cfg[0] * p;
  float next = rnd[tid] - dt_all[st] * dphi;
  if (tid == 0) out[0] = (float)(st + 1);
  out[1 + tid] = next;
}

// ---------------- launch ------------------------------------------------------------
extern "C" void kernel_launch(void* const* d_in, const int* in_sizes, int n_in,
                              void* d_out, int out_size, void* d_ws, size_t ws_size,
                              hipStream_t stream) {
  const float* rnd   = (const float*)d_in[0];
  const float* dit   = (const float*)d_in[1];
  const float* feat  = (const float*)d_in[2];
  const float* cfg   = (const float*)d_in[3];
  const float* cfgm  = (const float*)d_in[4];
  const float* t_all = (const float*)d_in[5];
  const float* dt_al = (const float*)d_in[6];
  const float* cosq  = (const float*)d_in[7];
  const float* sinq  = (const float*)d_in[8];
  const float* W_in  = (const float*)d_in[9];
  const float* b_in  = (const float*)d_in[10];
  const float* ln1   = (const float*)d_in[11];
  const float* Wq    = (const float*)d_in[12];
  const float* Wk    = (const float*)d_in[13];
  const float* Wv    = (const float*)d_in[14];
  const float* Wo    = (const float*)d_in[15];
  const float* ln2   = (const float*)d_in[16];
  const float* Wg    = (const float*)d_in[17];
  const float* Wu    = (const float*)d_in[18];
  const float* Wd    = (const float*)d_in[19];
  const float* normw = (const float*)d_in[20];
  const float* Wout  = (const float*)d_in[21];
  const float* bout  = (const float*)d_in[22];
  const int*   step  = (const int*)d_in[23];
  float* ws = (float*)d_ws;

  k_embed<<<14, 256, 0, stream>>>(rnd, dit, feat, t_all, W_in, b_in, step, ws);
  for (int l = 0; l < NLAYER; l++) {
    k_qkv<<<dim3(2, 128), 256, 0, stream>>>(Wq, Wk, Wv, ln1, ws, l);
    k_red4<<<360, 256, 0, stream>>>(ws + QKVP_OFF, ws + QKV_OFF, 128, TOKENS * 1280, 0);
    k_attn<<<256, 256, 0, stream>>>(Wo, cosq, sinq, ws, l);
    k_red4<<<288, 256, 0, stream>>>(ws + OPP_OFF, ws + H_OFF, 256, TOKENS * HDIM, 1);
    k_gu<<<dim3(8, 32), 256, 0, stream>>>(Wg, Wu, ln2, ws, l);
    k_wd<<<256, 256, 0, stream>>>(Wd, ws, l);
    k_red4<<<288, 256, 0, stream>>>(ws + WDP_OFF, ws + H_OFF, 256, TOKENS * HDIM, 1);
  }
  k_out<<<8, 256, 0, stream>>>(Wout, normw, ws);
  k_final<<<1, 256, 0, stream>>>(rnd, cfg, cfgm, dt_al, bout, step, ws, (float*)d_out);
}